// Round 7
// baseline (248.731 us; speedup 1.0000x reference)
//
#include <hip/hip_runtime.h>

#define NQ 22
#define DIMN (1u << NQ)

// partials layout (floats, offset from P = ws + 2*DIMN)
// NOTE: regions are contiguous => P is 280 flat segments of 512 floats.
#define PG_OFF 0u          // genHi: 12 quantities x 512 blocks   (segs 0..11)
#define PM_OFF 6144u       // midA:  16 x 512                     (segs 12..27)
#define PL_OFF 14336u      // k_low: 110 x 1024                   (segs 28..247)
#define PF_OFF 126976u     // measF: 16 x 1024                    (segs 248..279)
#define CNT_OFF 143360u    // ticket counter (int)

// ---------------- compile-time circuit algebra (circuit is fixed) ----------------
struct MaskSet {
    unsigned L[NQ];      // CNOT-ring layer over GF(2): bit b of Lx = parity(x & L[b])
    unsigned Linv[NQ];
    unsigned xm[NQ];     // conjugated X masks
    unsigned zm[NQ];     // conjugated Z masks (suffix masks)
    unsigned frowHi[5];  // P-toggle masks for y bits 17..21 (columns of Linv)
};

constexpr MaskSet buildMasks() {
    MaskSet M{};
    for (int b = 0; b < NQ; ++b) M.L[b] = 1u << b;
    for (int q = 0; q < NQ; ++q) {
        int bc = NQ - 1 - q, bt = NQ - 1 - ((q + 1) % NQ);
        M.L[bt] ^= M.L[bc];
    }
    unsigned mat[NQ] = {}, aug[NQ] = {};
    for (int b = 0; b < NQ; ++b) { mat[b] = M.L[b]; aug[b] = 1u << b; }
    for (int col = 0; col < NQ; ++col) {
        int piv = col;
        while (!((mat[piv] >> col) & 1u)) ++piv;
        unsigned tm = mat[piv]; mat[piv] = mat[col]; mat[col] = tm;
        unsigned ta = aug[piv]; aug[piv] = aug[col]; aug[col] = ta;
        for (int r = 0; r < NQ; ++r)
            if (r != col && ((mat[r] >> col) & 1u)) { mat[r] ^= mat[col]; aug[r] ^= aug[col]; }
    }
    for (int b = 0; b < NQ; ++b) M.Linv[b] = aug[b];
    for (int j = 0; j < NQ; ++j) {
        int b = NQ - 1 - j;
        unsigned xmv = 0;
        for (int r = 0; r < NQ; ++r)
            if ((aug[r] >> b) & 1u) xmv |= 1u << r;
        M.xm[j] = xmv;       // q0..9: {21-j,20-j}; q10..20: low pairs; q21: {0,20,21}
        M.zm[j] = M.L[b];    // suffix masks
    }
    for (int j = 0; j < 5; ++j) {
        unsigned f = 0;
        for (int r = 0; r < NQ; ++r)
            if ((aug[r] >> (17 + j)) & 1u) f |= 1u << r;
        M.frowHi[j] = f;
    }
    return M;
}
constexpr int topbit_c(unsigned v) { int b = 0; while (v >> (b + 1)) ++b; return b; }
constexpr unsigned unionHi() {
    MaskSet M = buildMasks();
    unsigned u = 0;
    for (int j = 0; j < 5; ++j) u |= M.frowHi[j];
    return u;
}
static_assert((unionHi() & 0xFFFFu) == 0, "frowHi must only touch bits 16..21");

// q0 and q21 share the same f4 pair mask; q4, q9 have their own (all 2-bit, low bits clear)
constexpr bool measPlanOK() {
    MaskSet M = buildMasks();
    if ((M.xm[0] >> 2) != (M.xm[21] >> 2)) return false;
    if ((M.xm[0] & 3u) != 0u) return false;
    if ((M.xm[21] & 3u) != 1u) return false;
    if ((M.xm[4] & 3u) != 0u) return false;
    if ((M.xm[9] & 3u) != 0u) return false;
    if (topbit_c(M.xm[0] >> 2) != 19) return false;
    if (topbit_c(M.xm[4] >> 2) != 15) return false;
    if (topbit_c(M.xm[9] >> 2) != 10) return false;
    return true;
}
static_assert(measPlanOK(), "measF pass plan must hold");

// sanity for the k_low bit plan
constexpr bool lowPlanOK() {
    MaskSet M = buildMasks();
    if ((M.xm[10] & ~0xE00u) != 0) return false;
    if ((M.xm[11] & ~0xE00u) != 0) return false;
    for (int q = 12; q <= 19; ++q) {
        if ((M.xm[q] & 3u) != 0 && (M.xm[q] & 3u) != 2u) return false;
        if ((M.zm[q] & 3u) != 0) return false;
        if (topbit_c(M.xm[q]) < 2 || topbit_c(M.xm[q]) > 9) return false;
    }
    if (M.xm[20] != 3u) return false;
    if ((M.zm[20] & 3u) != 2u) return false;
    return true;
}
static_assert(lowPlanOK(), "k_low measurement plan must hold");

__device__ __forceinline__ float fflip(float v, unsigned sbit31) {
    return __int_as_float(__float_as_int(v) ^ (int)sbit31);
}
__device__ __forceinline__ unsigned ph4(unsigned g) { return g ^ ((g >> 6) & 3u); }

// element-addressed LDS bank map for the k_low exchange phases.
__device__ __forceinline__ unsigned sA(unsigned i) {
    return i ^ ((i >> 3) & 7u) ^ (((i >> 6) & 3u) << 3);
}

// 4-quantity wave reduction: 7 shfl instead of 24.
// Returns: lane L holds the full-wave total of quantity (L&3).
__device__ __forceinline__ float fold4(float a, float b, float c, float d, int lane) {
    bool p0 = (lane & 1) != 0;
    float kL = p0 ? b : a, sL = p0 ? a : b;
    kL += __shfl_xor(sL, 1);
    float kH = p0 ? d : c, sH = p0 ? c : d;
    kH += __shfl_xor(sH, 1);
    bool p1 = (lane & 2) != 0;
    float k2 = p1 ? kH : kL, s2 = p1 ? kL : kH;
    k2 += __shfl_xor(s2, 2);
    k2 += __shfl_xor(k2, 4);
    k2 += __shfl_xor(k2, 8);
    k2 += __shfl_xor(k2, 16);
    k2 += __shfl_xor(k2, 32);
    return k2;
}

// per-block trig table build: trig[l*2NQ + b] = cos, trig[l*2NQ + NQ + b] = sin
__device__ __forceinline__ void buildTrig(float* trig, const float* __restrict__ theta, int t) {
    if (t < 2 * NQ) {
        int l = t / NQ, q = t % NQ, b = NQ - 1 - q;
        float h = 0.5f * theta[t];
        trig[l * 2 * NQ + b]      = cosf(h);
        trig[l * 2 * NQ + NQ + b] = sinf(h);
    }
}

// 3 RY gates on local element bits 0..2 (global bits b0..b0+2) for both states
__device__ __forceinline__ void gates3(float* a, float* b, const float* trig, int b0) {
#pragma unroll
    for (int g = 0; g < 3; ++g) {
        float c = trig[2 * NQ + b0 + g], s = trig[3 * NQ + b0 + g];
#pragma unroll
        for (int e = 0; e < 8; ++e) {
            if (!(e & (1 << g))) {
                int e1 = e | (1 << g);
                float x0 = a[e], x1 = a[e1];
                a[e] = c * x0 - s * x1; a[e1] = s * x0 + c * x1;
                float y0 = b[e], y1 = b[e1];
                b[e] = c * y0 - s * y1; b[e1] = s * y0 + c * y1;
            }
        }
    }
}

// segment -> accv slot mapping for the final reduce (280 segments of 512 floats)
__device__ __forceinline__ int slotOf(int s) {
    if (s < 12)  return 4 + s;                 // genHi q1..q3
    if (s < 28)  return 8 + s;                 // midA q5..q8 (20 + s-12)
    if (s < 248) {
        int r = (s - 28) >> 1;                 // k_low row (two halves per row)
        return (r < 44) ? (40 + r) : (88 + (r - 44));
    }
    int j = (s - 248) >> 1;                    // measF: two segs per quantity
    int qi = j >> 2;
    int b4 = (qi == 0) ? 0 : (qi == 1) ? 16 : (qi == 2) ? 36 : 84;
    return b4 + (j & 3);
}

// single measS-style pair accumulation (proven algebra from the original k_measS):
// pair (g, gx=g^mg4), within-f4 swap ml2 (0 or 1), z mask zm; adds into acc[4].
__device__ __forceinline__ void accPair(float4 a0, float4 a1, float4 b0in, float4 b1in,
                                        unsigned g, unsigned gx, unsigned ml2, unsigned zm,
                                        float* acc) {
    float4 b0 = b0in, b1 = b1in;
    if (ml2) {
        b0 = make_float4(b0.y, b0.x, b0.w, b0.z);
        b1 = make_float4(b1.y, b1.x, b1.w, b1.z);
    }
    unsigned zl = zm & 3u;
    unsigned fg = (((unsigned)__popc((g  << 2) & zm) & 1u) << 31);
    unsigned fx = (((unsigned)__popc((gx << 2) & zm) & 1u) << 31);
    const float* A0 = &a0.x; const float* A1 = &a1.x;
    const float* B0 = &b0.x; const float* B1 = &b1.x;
#pragma unroll
    for (int j = 0; j < 4; ++j) {
        unsigned pg31 = (((unsigned)__popc((unsigned)j & zl) & 1u) << 31);
        unsigned px31 = (((unsigned)__popc(((unsigned)j ^ ml2) & zl) & 1u) << 31);
        acc[0] += A0[j] * B0[j];
        acc[1] += A1[j] * B1[j];
        float p = A0[j] * B1[j], r = B0[j] * A1[j];
        acc[2] += p + r;
        acc[3] += fflip(p, fx ^ px31) + fflip(r, fg ^ pg31);
    }
}

// ---- generator in e=bits17..21 tile + gates 17..21 + measure q1,q2,q3 ----
__global__ __launch_bounds__(256, 1) void k_genHi(float* __restrict__ phi,
                                                  const float* __restrict__ theta,
                                                  float* __restrict__ P) {
    constexpr MaskSet M = buildMasks();
    __shared__ float red[4 * 12];
    __shared__ float trig[4 * NQ];
    if (blockIdx.x == 0 && threadIdx.x == 0) *(int*)(P + CNT_OFF) = 0;  // ticket reset
    buildTrig(trig, theta, threadIdx.x);
    __syncthreads();
    unsigned base = blockIdx.x * 256u + threadIdx.x;       // y bits 0..16
    unsigned P0 = 0;
#pragma unroll
    for (int b = 0; b < NQ; ++b)
        P0 |= ((unsigned)__popc(base & M.Linv[b]) & 1u) << b;
    float pc = 1.f;
#pragma unroll
    for (int b = 1; b < 16; ++b) {
        float cvb = trig[b], svb = trig[NQ + b];
        pc *= ((P0 >> b) & 1u) ? svb : cvb;
    }
    float cv0 = trig[0], sv0 = trig[NQ];
    float C0 = pc * ((P0 & 1u) ? sv0 : cv0);
    float C1 = pc * ((P0 & 1u) ? cv0 : -sv0);
    float cb[6], sb[6];
#pragma unroll
    for (int k = 0; k < 6; ++k) { cb[k] = trig[16 + k]; sb[k] = trig[NQ + 16 + k]; }
    unsigned u0 = P0 >> 16;                                // 6 bits
    float v0[32], v1[32];
#pragma unroll
    for (int e = 0; e < 32; ++e) {
        unsigned F = 0;
        if (e & 1)  F ^= M.frowHi[0];
        if (e & 2)  F ^= M.frowHi[1];
        if (e & 4)  F ^= M.frowHi[2];
        if (e & 8)  F ^= M.frowHi[3];
        if (e & 16) F ^= M.frowHi[4];
        unsigned u = u0 ^ (F >> 16);
        float vp = (u & 1u) ? sb[0] : cb[0];
#pragma unroll
        for (int k = 1; k < 6; ++k) vp *= ((u >> k) & 1u) ? sb[k] : cb[k];
        v0[e] = vp * C0;
        v1[e] = vp * C1;
    }
    float c2[5], s2[5];
#pragma unroll
    for (int j = 0; j < 5; ++j) {
        c2[j] = trig[2 * NQ + 17 + j];
        s2[j] = trig[3 * NQ + 17 + j];
    }
#pragma unroll
    for (int j = 0; j < 5; ++j) {
#pragma unroll
        for (int e = 0; e < 32; ++e) {
            if (!(e & (1 << j))) {
                int e1 = e | (1 << j);
                float a0 = v0[e], a1 = v0[e1];
                v0[e]  = c2[j] * a0 - s2[j] * a1;
                v0[e1] = s2[j] * a0 + c2[j] * a1;
                float b0 = v1[e], b1 = v1[e1];
                v1[e]  = c2[j] * b0 - s2[j] * b1;
                v1[e1] = s2[j] * b0 + c2[j] * b1;
            }
        }
    }
#pragma unroll
    for (int e = 0; e < 32; ++e) {
        unsigned a = base | ((unsigned)e << 17);
        phi[a] = v0[e];
        phi[DIMN + a] = v1[e];
    }
    // measure q1..q3 (x-pairs and z-masks entirely within bits 17..21)
    int lane = threadIdx.x & 63, w = threadIdx.x >> 6;
#pragma unroll
    for (int i = 1; i <= 3; ++i) {
        unsigned ex  = M.xm[i] >> 17;
        unsigned zme = M.zm[i] >> 17;
        float t00 = 0.f, t11 = 0.f, t01 = 0.f, u01 = 0.f;
#pragma unroll
        for (int e = 0; e < 32; ++e) {
            int ep = e ^ (int)ex;
            t00 += v0[e] * v0[ep];
            t11 += v1[e] * v1[ep];
            float p = v0[e] * v1[ep];
            t01 += p;
            unsigned sg = ((unsigned)__popc((unsigned)ep & zme) & 1u) << 31;
            u01 += fflip(p, sg);
        }
        float r = fold4(t00, t11, t01, u01, lane);
        if (lane < 4) red[w * 12 + (i - 1) * 4 + lane] = r;
    }
    __syncthreads();
    int t = threadIdx.x;
    if (t < 12) {
        float r = red[t] + red[12 + t] + red[24 + t] + red[36 + t];
        P[PG_OFF + (unsigned)t * 512u + blockIdx.x] = r;
    }
}

// ---- e=bits12..16 tile: gates 12..16 + measure q5..q8 ----
__global__ __launch_bounds__(256, 1) void k_midA(float* __restrict__ phi,
                                                 const float* __restrict__ theta,
                                                 float* __restrict__ P) {
    constexpr MaskSet M = buildMasks();
    __shared__ float red[4 * 16];
    __shared__ float trig[4 * NQ];
    buildTrig(trig, theta, threadIdx.x);
    __syncthreads();
    unsigned tid = blockIdx.x * 256u + threadIdx.x;        // [0, 2^17)
    unsigned base = (tid & 0xFFFu) | ((tid >> 12) << 17);  // bits 0..11 + 17..21
    float v0[32], v1[32];
#pragma unroll
    for (int e = 0; e < 32; ++e) {
        unsigned a = base | ((unsigned)e << 12);
        v0[e] = phi[a];
        v1[e] = phi[DIMN + a];
    }
    float c[5], s[5];
#pragma unroll
    for (int j = 0; j < 5; ++j) {
        c[j] = trig[2 * NQ + 12 + j];
        s[j] = trig[3 * NQ + 12 + j];
    }
#pragma unroll
    for (int j = 0; j < 5; ++j) {
#pragma unroll
        for (int e = 0; e < 32; ++e) {
            if (!(e & (1 << j))) {
                int e1 = e | (1 << j);
                float a0 = v0[e], a1 = v0[e1];
                v0[e]  = c[j] * a0 - s[j] * a1;
                v0[e1] = s[j] * a0 + c[j] * a1;
                float b0 = v1[e], b1 = v1[e1];
                v1[e]  = c[j] * b0 - s[j] * b1;
                v1[e1] = s[j] * b0 + c[j] * b1;
            }
        }
    }
#pragma unroll
    for (int e = 0; e < 32; ++e) {
        unsigned a = base | ((unsigned)e << 12);
        phi[a] = v0[e];
        phi[DIMN + a] = v1[e];
    }
    // measure q5..q8 (x-pairs within bits 12..16; z-masks suffix >= 13)
    int lane = threadIdx.x & 63, w = threadIdx.x >> 6;
#pragma unroll
    for (int i = 5; i <= 8; ++i) {
        unsigned ex  = (M.xm[i] >> 12) & 31u;
        unsigned zme = (M.zm[i] >> 12) & 31u;
        unsigned bs31 = ((unsigned)__popc(base & M.zm[i]) & 1u) << 31;
        float t00 = 0.f, t11 = 0.f, t01 = 0.f, u01 = 0.f;
#pragma unroll
        for (int e = 0; e < 32; ++e) {
            int ep = e ^ (int)ex;
            t00 += v0[e] * v0[ep];
            t11 += v1[e] * v1[ep];
            float p = v0[e] * v1[ep];
            t01 += p;
            unsigned sg = ((unsigned)__popc((unsigned)ep & zme) & 1u) << 31;
            u01 += fflip(p, sg ^ bs31);
        }
        float r = fold4(t00, t11, t01, u01, lane);
        if (lane < 4) red[w * 16 + (i - 5) * 4 + lane] = r;
    }
    __syncthreads();
    int t = threadIdx.x;
    if (t < 16) {
        float r = red[t] + red[16 + t] + red[32 + t] + red[48 + t];
        P[PM_OFF + (unsigned)t * 512u + blockIdx.x] = r;
    }
}

// ---- RY layer 2 bits 0..11 + q10..q20 X/Y + ALL Z measurements ----
// 512 threads, 8 elems/thread, 4 exchange phases
__global__ __launch_bounds__(512, 4) void k_low(float* __restrict__ phi,
                                                const float* __restrict__ theta,
                                                float* __restrict__ P) {
    constexpr MaskSet M = buildMasks();
    __shared__ float As[4096];
    __shared__ float Bs[4096];
    __shared__ float redZ[8 * 33];
    __shared__ float redQ[8 * 44];
    __shared__ float trig[4 * NQ];
    float4* As4 = (float4*)As;
    float4* Bs4 = (float4*)Bs;
    int t = threadIdx.x;
    int lane = t & 63, w = t >> 6;
    unsigned base = blockIdx.x * 4096u;
    float a[8], b[8];
    buildTrig(trig, theta, t);

    // ---- P0: load (8 consecutive elems/thread), gates bits 0..2, store ----
    {
        const float4* g0 = (const float4*)(phi + base);
        const float4* g1 = (const float4*)(phi + DIMN + base);
        float4 va0 = g0[2 * t], va1 = g0[2 * t + 1];
        float4 vb0 = g1[2 * t], vb1 = g1[2 * t + 1];
        a[0] = va0.x; a[1] = va0.y; a[2] = va0.z; a[3] = va0.w;
        a[4] = va1.x; a[5] = va1.y; a[6] = va1.z; a[7] = va1.w;
        b[0] = vb0.x; b[1] = vb0.y; b[2] = vb0.z; b[3] = vb0.w;
        b[4] = vb1.x; b[5] = vb1.y; b[6] = vb1.z; b[7] = vb1.w;
        __syncthreads();               // trig ready
        gates3(a, b, trig, 0);
#pragma unroll
        for (int j = 0; j < 8; ++j) {
            unsigned i = ((unsigned)t << 3) | (unsigned)j;
            unsigned A = sA(i);
            As[A] = a[j]; Bs[A] = b[j];
        }
    }
    __syncthreads();

    // ---- X01 read (j = bits 3..5), gates 3..5, write back same addresses ----
    {
#pragma unroll
        for (int j = 0; j < 8; ++j) {
            unsigned i = (((unsigned)t >> 3) << 6) | ((unsigned)j << 3) | ((unsigned)t & 7u);
            unsigned A = sA(i);
            a[j] = As[A]; b[j] = Bs[A];
        }
        gates3(a, b, trig, 3);
#pragma unroll
        for (int j = 0; j < 8; ++j) {
            unsigned i = (((unsigned)t >> 3) << 6) | ((unsigned)j << 3) | ((unsigned)t & 7u);
            unsigned A = sA(i);
            As[A] = a[j]; Bs[A] = b[j];
        }
    }
    __syncthreads();

    // ---- X12 read (j = bits 6..8), gates 6..8, write back ----
    {
#pragma unroll
        for (int j = 0; j < 8; ++j) {
            unsigned i = (((unsigned)t >> 6) << 9) | ((unsigned)j << 6) | ((unsigned)t & 63u);
            unsigned A = sA(i);
            a[j] = As[A]; b[j] = Bs[A];
        }
        gates3(a, b, trig, 6);
#pragma unroll
        for (int j = 0; j < 8; ++j) {
            unsigned i = (((unsigned)t >> 6) << 9) | ((unsigned)j << 6) | ((unsigned)t & 63u);
            unsigned A = sA(i);
            As[A] = a[j]; Bs[A] = b[j];
        }
    }
    __syncthreads();

    // ---- X23 read (j = bits 9..11), gates 9..11 ----
    {
#pragma unroll
        for (int j = 0; j < 8; ++j) {
            unsigned i = ((unsigned)j << 9) | (unsigned)t;
            unsigned A = sA(i);
            a[j] = As[A]; b[j] = Bs[A];
        }
        gates3(a, b, trig, 9);
    }
    __syncthreads();   // protect As/Bs before measurement-layout overwrite

    // ---- write phi + measurement-layout LDS (elem i at i ^ (((i>>8)&3)<<2)) ----
#pragma unroll
    for (int j = 0; j < 8; ++j) {
        unsigned i = ((unsigned)j << 9) | (unsigned)t;
        phi[base + i] = a[j];
        phi[DIMN + base + i] = b[j];
        unsigned p = i ^ (((i >> 8) & 3u) << 2);
        As[p] = a[j]; Bs[p] = b[j];
    }

    // ---- fused Z measurement from regs: 3-level tree (bits 9..11) + lane Walsh ----
#pragma unroll
    for (int c = 0; c < 3; ++c) {
        float p[8];
#pragma unroll
        for (int j = 0; j < 8; ++j)
            p[j] = (c == 0) ? a[j] * a[j] : (c == 1) ? b[j] * b[j] : a[j] * b[j];
        float s1[4], d1[4];
#pragma unroll
        for (int j = 0; j < 4; ++j) { s1[j] = p[j] + p[j + 4]; d1[j] = p[j] - p[j + 4]; }
        float s2_0 = s1[0] + s1[2], s2_1 = s1[1] + s1[3];
        float d2_0 = d1[0] - d1[2], d2_1 = d1[1] - d1[3];
        float SS = s2_0 + s2_1;
        float z0 = (d1[0] + d1[1]) + (d1[2] + d1[3]);     // sign: bit 11
        float z1 = d2_0 + d2_1;                           // sign: bits 11,10
        float d3 = d2_0 - d2_1;                           // sign: bits 11,10,9
        float r = fold4(SS, z0, z1, 0.f, lane);
        if (lane < 3) redZ[w * 33 + c * 11 + lane] = r;
        float v = d3;
#pragma unroll
        for (int s = 0; s < 6; ++s) {
            float u = __shfl_xor(v, 1 << s);
            v = u + fflip(v, ((unsigned)(lane >> s) & 1u) << 31);
        }
        int pcnt = __popc(lane);
        if (lane == 64 - (64 >> pcnt)) redZ[w * 33 + c * 11 + 3 + pcnt] = v;
    }
    __syncthreads();   // redZ + measurement-layout As/Bs visible

    // ---- Z combine over 8 waves with wave-bit signs (elem bits 6..8) ----
    if (t < 66) {
        int c = t % 3, q = t / 3;
        int idx, wm;
        if (q == 0 || q == 21)      { idx = 9; wm = 7; }   // full suffix
        else if (q <= 9)            { idx = 0; wm = 0; }   // SS (suffix above tile)
        else if (q == 10)           { idx = 1; wm = 0; }
        else if (q == 11)           { idx = 2; wm = 0; }
        else if (q == 12)           { idx = 3; wm = 0; }
        else if (q == 13)           { idx = 3; wm = 4; }
        else if (q == 14)           { idx = 3; wm = 6; }
        else if (q == 15)           { idx = 3; wm = 7; }
        else                        { idx = q - 12; wm = 7; }  // q16..q20 -> 4..8
        float val = 0.f;
#pragma unroll
        for (int ww = 0; ww < 8; ++ww) {
            float rv = redZ[ww * 33 + c * 11 + idx];
            val += ((__popc(ww & wm) & 1) ? -rv : rv);
        }
        unsigned sg = (unsigned)__popc(base & M.zm[q]) & 1u;
        P[PL_OFF + (44u + (unsigned)t) * 1024u + blockIdx.x] = sg ? -val : val;
    }

    // ---- q10,q11 from registers (x-pairs within bits 9..11 = j bits) ----
#pragma unroll
    for (int i = 0; i < 2; ++i) {
        int q = 10 + i;
        unsigned je  = (M.xm[q] >> 9) & 7u;
        unsigned zmj = (M.zm[q] >> 9) & 7u;
        unsigned zb31 = ((unsigned)__popc(base & M.zm[q]) & 1u) << 31;
        float t00 = 0.f, t11 = 0.f, t01 = 0.f, u01 = 0.f;
#pragma unroll
        for (int j = 0; j < 8; ++j) {
            int jp = j ^ (int)je;
            t00 += a[j] * a[jp];
            t11 += b[j] * b[jp];
            float p = a[j] * b[jp];
            t01 += p;
            unsigned sg = ((unsigned)__popc((unsigned)jp & zmj) & 1u) << 31;
            u01 += fflip(p, sg ^ zb31);
        }
        float r = fold4(t00, t11, t01, u01, lane);
        if (lane < 4) redQ[w * 44 + 4 * i + lane] = r;
    }

    // ---- q12..q19 (generic float4-pair path), q20 special ----
#pragma unroll
    for (int iq = 2; iq < 10; ++iq) {
        int q = 10 + iq;
        unsigned m = M.xm[q], zm = M.zm[q];
        unsigned zb = (unsigned)__popc(base & zm) & 1u;
        int gb = topbit_c(M.xm[q]) - 2;
        unsigned mg4 = m >> 2;
        unsigned swap2 = m & 3u;            // 0 or 2
        float t00 = 0.f, t11 = 0.f, t01 = 0.f, u01 = 0.f;
        unsigned gc = (unsigned)t;          // 0..511: covers all 512 half-pairs
        unsigned g = ((gc >> gb) << (gb + 1)) | (gc & ((1u << gb) - 1u));
        unsigned gx = g ^ mg4;
        float4 a0 = As4[ph4(g)],  a1 = Bs4[ph4(g)];
        float4 b0 = As4[ph4(gx)], b1 = Bs4[ph4(gx)];
        if (swap2) {
            b0 = make_float4(b0.z, b0.w, b0.x, b0.y);
            b1 = make_float4(b1.z, b1.w, b1.x, b1.y);
        }
        unsigned szg = ((unsigned)__popc((g << 2) & zm) + zb) & 1u;
        unsigned szx = ((unsigned)__popc((gx << 2) & zm) + zb) & 1u;
        unsigned fg = szg << 31, fx = szx << 31;
        const float* A0 = &a0.x; const float* A1 = &a1.x;
        const float* B0 = &b0.x; const float* B1 = &b1.x;
#pragma unroll
        for (int j = 0; j < 4; ++j) {
            t00 += A0[j] * B0[j];
            t11 += A1[j] * B1[j];
            float p = A0[j] * B1[j], r2 = B0[j] * A1[j];
            t01 += p + r2;
            u01 += fflip(p, fx) + fflip(r2, fg);
        }
        t00 *= 2.f; t11 *= 2.f;
        float r = fold4(t00, t11, t01, u01, lane);
        if (lane < 4) redQ[w * 44 + 4 * iq + lane] = r;
    }
    {
        // q20: m = 3, partner within float4; zm&3 == 2
        unsigned zm = M.zm[20];
        unsigned zb = (unsigned)__popc(base & zm) & 1u;
        float t00 = 0.f, t11 = 0.f, t01 = 0.f, u01 = 0.f;
#pragma unroll
        for (int k = 0; k < 2; ++k) {
            unsigned g = (unsigned)t + 512u * k;
            float4 a0 = As4[ph4(g)], a1 = Bs4[ph4(g)];
            unsigned szg = ((unsigned)__popc((g << 2) & zm) + zb) & 1u;
            const float* A0 = &a0.x; const float* A1 = &a1.x;
#pragma unroll
            for (int j = 0; j < 4; ++j) {
                int jx = j ^ 3;
                float p = A0[j] * A0[jx];
                float q2 = A1[j] * A1[jx];
                float cr = A0[j] * A1[jx];
                t00 += p; t11 += q2; t01 += cr;
                unsigned sj = ((unsigned)(jx >> 1) & 1u) ^ szg;   // zm&3 == 2
                u01 += fflip(cr, sj << 31);
            }
        }
        float r = fold4(t00, t11, t01, u01, lane);
        if (lane < 4) redQ[w * 44 + 40 + lane] = r;
    }
    __syncthreads();
    if (t < 44) {
        float r = 0.f;
#pragma unroll
        for (int ww = 0; ww < 8; ++ww) r += redQ[ww * 44 + t];
        P[PL_OFF + (unsigned)t * 1024u + blockIdx.x] = r;
    }
}

// ------- X/Y measurements for q0,q4,q9,q21 in 3 small-live-set passes + FINAL reduce ----
// Pass A: pairs along GA=xm[0]>>2 -> q0 (ml2=0) AND q21 (ml2=1) from the same loads.
// Pass B: pairs along GB=xm[4]>>2 -> q4.  Pass C: pairs along GC=xm[9]>>2 -> q9.
// grid 1024x256: per pass 2^19 pairs -> 2 pairs/thread, 8 float4 live max.
__global__ __launch_bounds__(256) void k_measF(const float* __restrict__ phi,
                                               float* __restrict__ P,
                                               float* __restrict__ out) {
    constexpr MaskSet M = buildMasks();
    __shared__ float red[4 * 16];
    __shared__ float accv[160];
    __shared__ int lastBlk;
    const float4* P0 = (const float4*)phi;
    const float4* P1 = (const float4*)(phi + DIMN);
    unsigned tid = blockIdx.x * 256u + threadIdx.x;        // [0, 2^18)
    int lane = threadIdx.x & 63, w = threadIdx.x >> 6;
    float res[16];
#pragma unroll
    for (int k = 0; k < 16; ++k) res[k] = 0.f;

    // ---- pass A: q0 + q21 (shared pair mask, gb = 19) ----
    {
        constexpr unsigned mg4 = 0xC0000u;                 // xm[0]>>2 == xm[21]>>2
        constexpr unsigned zm0 = buildMasks().zm[0];
        constexpr unsigned zm21 = buildMasks().zm[21];
#pragma unroll
        for (int k = 0; k < 2; ++k) {
            unsigned g = tid + (unsigned)k * 262144u;      // pc < 2^19, bit19 == 0
            unsigned gx = g ^ mg4;
            float4 a0 = P0[g], a1 = P1[g];
            float4 b0 = P0[gx], b1 = P1[gx];
            accPair(a0, a1, b0, b1, g, gx, 0u, zm0,  &res[0]);   // q0
            accPair(a0, a1, b0, b1, g, gx, 1u, zm21, &res[12]);  // q21
        }
        res[0] *= 2.f; res[1] *= 2.f;
        res[12] *= 2.f; res[13] *= 2.f;
    }
    // ---- pass B: q4 (gb = 15) ----
    {
        constexpr unsigned mg4 = 0xC000u;                  // xm[4]>>2
        constexpr unsigned zm4 = buildMasks().zm[4];
#pragma unroll
        for (int k = 0; k < 2; ++k) {
            unsigned pc = tid + (unsigned)k * 262144u;
            unsigned g = ((pc >> 15) << 16) | (pc & 0x7FFFu);
            unsigned gx = g ^ mg4;
            float4 a0 = P0[g], a1 = P1[g];
            float4 b0 = P0[gx], b1 = P1[gx];
            accPair(a0, a1, b0, b1, g, gx, 0u, zm4, &res[4]);
        }
        res[4] *= 2.f; res[5] *= 2.f;
    }
    // ---- pass C: q9 (gb = 10) ----
    {
        constexpr unsigned mg4 = 0x600u;                   // xm[9]>>2
        constexpr unsigned zm9 = buildMasks().zm[9];
#pragma unroll
        for (int k = 0; k < 2; ++k) {
            unsigned pc = tid + (unsigned)k * 262144u;
            unsigned g = ((pc >> 10) << 11) | (pc & 0x3FFu);
            unsigned gx = g ^ mg4;
            float4 a0 = P0[g], a1 = P1[g];
            float4 b0 = P0[gx], b1 = P1[gx];
            accPair(a0, a1, b0, b1, g, gx, 0u, zm9, &res[8]);
        }
        res[8] *= 2.f; res[9] *= 2.f;
    }

#pragma unroll
    for (int g4 = 0; g4 < 4; ++g4) {
        float r = fold4(res[4 * g4 + 0], res[4 * g4 + 1], res[4 * g4 + 2], res[4 * g4 + 3], lane);
        if (lane < 4) red[w * 16 + 4 * g4 + lane] = r;
    }
    __syncthreads();
    int tt = threadIdx.x;
    if (tt < 16) {
        float r = red[tt] + red[16 + tt] + red[32 + tt] + red[48 + tt];
        P[PF_OFF + (unsigned)tt * 1024u + blockIdx.x] = r;   // order: q0,q4,q9,q21 (4 each)
    }
    // ---- ticket: last block to finish does the final reduction + loss ----
    __threadfence();
    __syncthreads();
    if (tt == 0) {
        int c = atomicAdd((int*)(P + CNT_OFF), 1);
        lastBlk = (c == (int)gridDim.x - 1);
    }
    __syncthreads();
    if (!lastBlk) return;
    __threadfence();

    // ---- wave-parallel coalesced reduce of 280 flat segments (512 floats each) ----
    if (tt < 160) accv[tt] = 0.f;
    __syncthreads();
    {
        const float4* Pf = (const float4*)P;
        int g0w = (w < 2) ? w * 18 : 36 + (w - 2) * 17;    // groups of 4 segments
        int ng  = (w < 2) ? 18 : 17;                       // 18+18+17+17 = 70 = 280/4
        for (int gi = 0; gi < ng; ++gi) {
            int s0 = (g0w + gi) * 4;
            float q[4];
#pragma unroll
            for (int k = 0; k < 4; ++k) {
                const float4* sp = Pf + (unsigned)(s0 + k) * 128u;
                float4 x = sp[lane];
                float4 y = sp[lane + 64];
                q[k] = ((x.x + x.y) + (x.z + x.w)) + ((y.x + y.y) + (y.z + y.w));
            }
            float r = fold4(q[0], q[1], q[2], q[3], lane);
            if (lane < 4) atomicAdd(&accv[slotOf(s0 + lane)], r);
        }
    }
    __syncthreads();
    float v = 0.f;
    if (tt < NQ) {
        float t00 = accv[4 * tt], t11 = accv[4 * tt + 1];
        float t01 = accv[4 * tt + 2], u01 = accv[4 * tt + 3];
        float d = t00 - t11;
        v = 0.5f * d * d + 2.f * t01 * t01 + 2.f * u01 * u01;   // X op + Y op
    } else if (tt < 2 * NQ) {
        int q = tt - NQ;
        float z0 = accv[88 + 3 * q], z1 = accv[88 + 3 * q + 1];
        float zz = accv[88 + 3 * q + 2];
        float d = z0 - z1;
        v = 0.5f * d * d + 2.f * zz * zz;                       // Z op
    }
    v += __shfl_down(v, 32); v += __shfl_down(v, 16); v += __shfl_down(v, 8);
    v += __shfl_down(v, 4);  v += __shfl_down(v, 2);  v += __shfl_down(v, 1);
    if (tt == 0) out[0] = v;
}

extern "C" void kernel_launch(void* const* d_in, const int* in_sizes, int n_in,
                              void* d_out, int out_size, void* d_ws, size_t ws_size,
                              hipStream_t stream) {
    const float* theta = (const float*)d_in[0];
    float* out  = (float*)d_out;
    float* ws   = (float*)d_ws;
    float* phi  = ws;                          // 2 * DIMN floats (32 MB)
    float* P    = ws + 2 * (size_t)DIMN;       // partials + ticket counter

    k_genHi<<<512, 256, 0, stream>>>(phi, theta, P);
    k_midA<<<512, 256, 0, stream>>>(phi, theta, P);
    k_low<<<1024, 512, 0, stream>>>(phi, theta, P);
    k_measF<<<1024, 256, 0, stream>>>(phi, P, out);
}

// Round 8
// 200.086 us; speedup vs baseline: 1.2431x; 1.2431x over previous
//
#include <hip/hip_runtime.h>

#define NQ 22
#define DIMN (1u << NQ)

// partials layout (floats, offset from P = ws + 2*DIMN)
// NOTE: regions are contiguous => P is 264 flat segments of 512 floats.
#define PG_OFF 0u          // genHi: 12 quantities x 512 blocks   (segs 0..11)
#define PM_OFF 6144u       // midA:  16 x 512                     (segs 12..27)
#define PL_OFF 14336u      // k_low: 110 x 1024                   (segs 28..247)
#define PF_OFF 126976u     // measF: 16 rows x 512 (half padded)  (segs 248..263)
#define CNT_OFF 135168u    // ticket counter (int)

// ---------------- compile-time circuit algebra (circuit is fixed) ----------------
struct MaskSet {
    unsigned L[NQ];      // CNOT-ring layer over GF(2): bit b of Lx = parity(x & L[b])
    unsigned Linv[NQ];
    unsigned xm[NQ];     // conjugated X masks
    unsigned zm[NQ];     // conjugated Z masks (suffix masks)
    unsigned frowHi[5];  // P-toggle masks for y bits 17..21 (columns of Linv)
};

constexpr MaskSet buildMasks() {
    MaskSet M{};
    for (int b = 0; b < NQ; ++b) M.L[b] = 1u << b;
    for (int q = 0; q < NQ; ++q) {
        int bc = NQ - 1 - q, bt = NQ - 1 - ((q + 1) % NQ);
        M.L[bt] ^= M.L[bc];
    }
    unsigned mat[NQ] = {}, aug[NQ] = {};
    for (int b = 0; b < NQ; ++b) { mat[b] = M.L[b]; aug[b] = 1u << b; }
    for (int col = 0; col < NQ; ++col) {
        int piv = col;
        while (!((mat[piv] >> col) & 1u)) ++piv;
        unsigned tm = mat[piv]; mat[piv] = mat[col]; mat[col] = tm;
        unsigned ta = aug[piv]; aug[piv] = aug[col]; aug[col] = ta;
        for (int r = 0; r < NQ; ++r)
            if (r != col && ((mat[r] >> col) & 1u)) { mat[r] ^= mat[col]; aug[r] ^= aug[col]; }
    }
    for (int b = 0; b < NQ; ++b) M.Linv[b] = aug[b];
    for (int j = 0; j < NQ; ++j) {
        int b = NQ - 1 - j;
        unsigned xmv = 0;
        for (int r = 0; r < NQ; ++r)
            if ((aug[r] >> b) & 1u) xmv |= 1u << r;
        M.xm[j] = xmv;       // q0..9: {21-j,20-j}; q10..20: low pairs; q21: {0,20,21}
        M.zm[j] = M.L[b];    // suffix masks
    }
    for (int j = 0; j < 5; ++j) {
        unsigned f = 0;
        for (int r = 0; r < NQ; ++r)
            if ((aug[r] >> (17 + j)) & 1u) f |= 1u << r;
        M.frowHi[j] = f;
    }
    return M;
}
constexpr int topbit_c(unsigned v) { int b = 0; while (v >> (b + 1)) ++b; return b; }
constexpr unsigned unionHi() {
    MaskSet M = buildMasks();
    unsigned u = 0;
    for (int j = 0; j < 5; ++j) u |= M.frowHi[j];
    return u;
}
static_assert((unionHi() & 0xFFFFu) == 0, "frowHi must only touch bits 16..21");

// q0 and q21 share the same f4 pair mask; q4, q9 have their own (all 2-bit, low bits clear)
constexpr bool measPlanOK() {
    MaskSet M = buildMasks();
    if ((M.xm[0] >> 2) != (M.xm[21] >> 2)) return false;
    if ((M.xm[0] & 3u) != 0u) return false;
    if ((M.xm[21] & 3u) != 1u) return false;
    if ((M.xm[4] & 3u) != 0u) return false;
    if ((M.xm[9] & 3u) != 0u) return false;
    if (topbit_c(M.xm[0] >> 2) != 19) return false;
    if (topbit_c(M.xm[4] >> 2) != 15) return false;
    if (topbit_c(M.xm[9] >> 2) != 10) return false;
    return true;
}
static_assert(measPlanOK(), "measF slice plan must hold");

// sanity for the k_low bit plan
constexpr bool lowPlanOK() {
    MaskSet M = buildMasks();
    if ((M.xm[10] & ~0xE00u) != 0) return false;
    if ((M.xm[11] & ~0xE00u) != 0) return false;
    for (int q = 12; q <= 19; ++q) {
        if ((M.xm[q] & 3u) != 0 && (M.xm[q] & 3u) != 2u) return false;
        if ((M.zm[q] & 3u) != 0) return false;
        if (topbit_c(M.xm[q]) < 2 || topbit_c(M.xm[q]) > 9) return false;
    }
    if (M.xm[20] != 3u) return false;
    if ((M.zm[20] & 3u) != 2u) return false;
    return true;
}
static_assert(lowPlanOK(), "k_low measurement plan must hold");

__device__ __forceinline__ float fflip(float v, unsigned sbit31) {
    return __int_as_float(__float_as_int(v) ^ (int)sbit31);
}
__device__ __forceinline__ unsigned ph4(unsigned g) { return g ^ ((g >> 6) & 3u); }

// element-addressed LDS bank map for the k_low exchange phases.
__device__ __forceinline__ unsigned sA(unsigned i) {
    return i ^ ((i >> 3) & 7u) ^ (((i >> 6) & 3u) << 3);
}

// 4-quantity wave reduction: 7 shfl instead of 24.
// Returns: lane L holds the full-wave total of quantity (L&3).
__device__ __forceinline__ float fold4(float a, float b, float c, float d, int lane) {
    bool p0 = (lane & 1) != 0;
    float kL = p0 ? b : a, sL = p0 ? a : b;
    kL += __shfl_xor(sL, 1);
    float kH = p0 ? d : c, sH = p0 ? c : d;
    kH += __shfl_xor(sH, 1);
    bool p1 = (lane & 2) != 0;
    float k2 = p1 ? kH : kL, s2 = p1 ? kL : kH;
    k2 += __shfl_xor(s2, 2);
    k2 += __shfl_xor(k2, 4);
    k2 += __shfl_xor(k2, 8);
    k2 += __shfl_xor(k2, 16);
    k2 += __shfl_xor(k2, 32);
    return k2;
}

// per-block trig table build: trig[l*2NQ + b] = cos, trig[l*2NQ + NQ + b] = sin
__device__ __forceinline__ void buildTrig(float* trig, const float* __restrict__ theta, int t) {
    if (t < 2 * NQ) {
        int l = t / NQ, q = t % NQ, b = NQ - 1 - q;
        float h = 0.5f * theta[t];
        trig[l * 2 * NQ + b]      = cosf(h);
        trig[l * 2 * NQ + NQ + b] = sinf(h);
    }
}

// 3 RY gates on local element bits 0..2 (global bits b0..b0+2) for both states
__device__ __forceinline__ void gates3(float* a, float* b, const float* trig, int b0) {
#pragma unroll
    for (int g = 0; g < 3; ++g) {
        float c = trig[2 * NQ + b0 + g], s = trig[3 * NQ + b0 + g];
#pragma unroll
        for (int e = 0; e < 8; ++e) {
            if (!(e & (1 << g))) {
                int e1 = e | (1 << g);
                float x0 = a[e], x1 = a[e1];
                a[e] = c * x0 - s * x1; a[e1] = s * x0 + c * x1;
                float y0 = b[e], y1 = b[e1];
                b[e] = c * y0 - s * y1; b[e1] = s * y0 + c * y1;
            }
        }
    }
}

// segment -> accv slot mapping for the final reduce (264 segments of 512 floats)
__device__ __forceinline__ int slotOf(int s) {
    if (s < 12)  return 4 + s;                 // genHi q1..q3
    if (s < 28)  return 8 + s;                 // midA q5..q8 (20 + s-12)
    if (s < 248) {
        int r = (s - 28) >> 1;                 // k_low row (two halves per row)
        return (r < 44) ? (40 + r) : (88 + (r - 44));
    }
    // measF rows: q0(0..3), q21(4..7), q4(8..11), q9(12..15)
    const int tbl[16] = { 0, 1, 2, 3, 84, 85, 86, 87, 16, 17, 18, 19, 36, 37, 38, 39 };
    return tbl[s - 248];
}

// single measS-style pair accumulation (proven algebra, rounds 6-7 refchecked):
// pair (g, gx=g^mg4), within-f4 swap ml2 (0 or 1), z mask zm; adds into acc[4].
__device__ __forceinline__ void accPair(float4 a0, float4 a1, float4 b0in, float4 b1in,
                                        unsigned g, unsigned gx, unsigned ml2, unsigned zm,
                                        float* acc) {
    float4 b0 = b0in, b1 = b1in;
    if (ml2) {
        b0 = make_float4(b0.y, b0.x, b0.w, b0.z);
        b1 = make_float4(b1.y, b1.x, b1.w, b1.z);
    }
    unsigned zl = zm & 3u;
    unsigned fg = (((unsigned)__popc((g  << 2) & zm) & 1u) << 31);
    unsigned fx = (((unsigned)__popc((gx << 2) & zm) & 1u) << 31);
    const float* A0 = &a0.x; const float* A1 = &a1.x;
    const float* B0 = &b0.x; const float* B1 = &b1.x;
#pragma unroll
    for (int j = 0; j < 4; ++j) {
        unsigned pg31 = (((unsigned)__popc((unsigned)j & zl) & 1u) << 31);
        unsigned px31 = (((unsigned)__popc(((unsigned)j ^ ml2) & zl) & 1u) << 31);
        acc[0] += A0[j] * B0[j];
        acc[1] += A1[j] * B1[j];
        float p = A0[j] * B1[j], r = B0[j] * A1[j];
        acc[2] += p + r;
        acc[3] += fflip(p, fx ^ px31) + fflip(r, fg ^ pg31);
    }
}

// ---- generator in e=bits17..21 tile + gates 17..21 + measure q1,q2,q3 ----
__global__ __launch_bounds__(256, 1) void k_genHi(float* __restrict__ phi,
                                                  const float* __restrict__ theta,
                                                  float* __restrict__ P) {
    constexpr MaskSet M = buildMasks();
    __shared__ float red[4 * 12];
    __shared__ float trig[4 * NQ];
    if (blockIdx.x == 0 && threadIdx.x == 0) *(int*)(P + CNT_OFF) = 0;  // ticket reset
    buildTrig(trig, theta, threadIdx.x);
    __syncthreads();
    unsigned base = blockIdx.x * 256u + threadIdx.x;       // y bits 0..16
    unsigned P0 = 0;
#pragma unroll
    for (int b = 0; b < NQ; ++b)
        P0 |= ((unsigned)__popc(base & M.Linv[b]) & 1u) << b;
    float pc = 1.f;
#pragma unroll
    for (int b = 1; b < 16; ++b) {
        float cvb = trig[b], svb = trig[NQ + b];
        pc *= ((P0 >> b) & 1u) ? svb : cvb;
    }
    float cv0 = trig[0], sv0 = trig[NQ];
    float C0 = pc * ((P0 & 1u) ? sv0 : cv0);
    float C1 = pc * ((P0 & 1u) ? cv0 : -sv0);
    float cb[6], sb[6];
#pragma unroll
    for (int k = 0; k < 6; ++k) { cb[k] = trig[16 + k]; sb[k] = trig[NQ + 16 + k]; }
    unsigned u0 = P0 >> 16;                                // 6 bits
    float v0[32], v1[32];
#pragma unroll
    for (int e = 0; e < 32; ++e) {
        unsigned F = 0;
        if (e & 1)  F ^= M.frowHi[0];
        if (e & 2)  F ^= M.frowHi[1];
        if (e & 4)  F ^= M.frowHi[2];
        if (e & 8)  F ^= M.frowHi[3];
        if (e & 16) F ^= M.frowHi[4];
        unsigned u = u0 ^ (F >> 16);
        float vp = (u & 1u) ? sb[0] : cb[0];
#pragma unroll
        for (int k = 1; k < 6; ++k) vp *= ((u >> k) & 1u) ? sb[k] : cb[k];
        v0[e] = vp * C0;
        v1[e] = vp * C1;
    }
    float c2[5], s2[5];
#pragma unroll
    for (int j = 0; j < 5; ++j) {
        c2[j] = trig[2 * NQ + 17 + j];
        s2[j] = trig[3 * NQ + 17 + j];
    }
#pragma unroll
    for (int j = 0; j < 5; ++j) {
#pragma unroll
        for (int e = 0; e < 32; ++e) {
            if (!(e & (1 << j))) {
                int e1 = e | (1 << j);
                float a0 = v0[e], a1 = v0[e1];
                v0[e]  = c2[j] * a0 - s2[j] * a1;
                v0[e1] = s2[j] * a0 + c2[j] * a1;
                float b0 = v1[e], b1 = v1[e1];
                v1[e]  = c2[j] * b0 - s2[j] * b1;
                v1[e1] = s2[j] * b0 + c2[j] * b1;
            }
        }
    }
#pragma unroll
    for (int e = 0; e < 32; ++e) {
        unsigned a = base | ((unsigned)e << 17);
        phi[a] = v0[e];
        phi[DIMN + a] = v1[e];
    }
    // measure q1..q3 (x-pairs and z-masks entirely within bits 17..21)
    int lane = threadIdx.x & 63, w = threadIdx.x >> 6;
#pragma unroll
    for (int i = 1; i <= 3; ++i) {
        unsigned ex  = M.xm[i] >> 17;
        unsigned zme = M.zm[i] >> 17;
        float t00 = 0.f, t11 = 0.f, t01 = 0.f, u01 = 0.f;
#pragma unroll
        for (int e = 0; e < 32; ++e) {
            int ep = e ^ (int)ex;
            t00 += v0[e] * v0[ep];
            t11 += v1[e] * v1[ep];
            float p = v0[e] * v1[ep];
            t01 += p;
            unsigned sg = ((unsigned)__popc((unsigned)ep & zme) & 1u) << 31;
            u01 += fflip(p, sg);
        }
        float r = fold4(t00, t11, t01, u01, lane);
        if (lane < 4) red[w * 12 + (i - 1) * 4 + lane] = r;
    }
    __syncthreads();
    int t = threadIdx.x;
    if (t < 12) {
        float r = red[t] + red[12 + t] + red[24 + t] + red[36 + t];
        P[PG_OFF + (unsigned)t * 512u + blockIdx.x] = r;
    }
}

// ---- e=bits12..16 tile: gates 12..16 + measure q5..q8 ----
__global__ __launch_bounds__(256, 1) void k_midA(float* __restrict__ phi,
                                                 const float* __restrict__ theta,
                                                 float* __restrict__ P) {
    constexpr MaskSet M = buildMasks();
    __shared__ float red[4 * 16];
    __shared__ float trig[4 * NQ];
    buildTrig(trig, theta, threadIdx.x);
    __syncthreads();
    unsigned tid = blockIdx.x * 256u + threadIdx.x;        // [0, 2^17)
    unsigned base = (tid & 0xFFFu) | ((tid >> 12) << 17);  // bits 0..11 + 17..21
    float v0[32], v1[32];
#pragma unroll
    for (int e = 0; e < 32; ++e) {
        unsigned a = base | ((unsigned)e << 12);
        v0[e] = phi[a];
        v1[e] = phi[DIMN + a];
    }
    float c[5], s[5];
#pragma unroll
    for (int j = 0; j < 5; ++j) {
        c[j] = trig[2 * NQ + 12 + j];
        s[j] = trig[3 * NQ + 12 + j];
    }
#pragma unroll
    for (int j = 0; j < 5; ++j) {
#pragma unroll
        for (int e = 0; e < 32; ++e) {
            if (!(e & (1 << j))) {
                int e1 = e | (1 << j);
                float a0 = v0[e], a1 = v0[e1];
                v0[e]  = c[j] * a0 - s[j] * a1;
                v0[e1] = s[j] * a0 + c[j] * a1;
                float b0 = v1[e], b1 = v1[e1];
                v1[e]  = c[j] * b0 - s[j] * b1;
                v1[e1] = s[j] * b0 + c[j] * b1;
            }
        }
    }
#pragma unroll
    for (int e = 0; e < 32; ++e) {
        unsigned a = base | ((unsigned)e << 12);
        phi[a] = v0[e];
        phi[DIMN + a] = v1[e];
    }
    // measure q5..q8 (x-pairs within bits 12..16; z-masks suffix >= 13)
    int lane = threadIdx.x & 63, w = threadIdx.x >> 6;
#pragma unroll
    for (int i = 5; i <= 8; ++i) {
        unsigned ex  = (M.xm[i] >> 12) & 31u;
        unsigned zme = (M.zm[i] >> 12) & 31u;
        unsigned bs31 = ((unsigned)__popc(base & M.zm[i]) & 1u) << 31;
        float t00 = 0.f, t11 = 0.f, t01 = 0.f, u01 = 0.f;
#pragma unroll
        for (int e = 0; e < 32; ++e) {
            int ep = e ^ (int)ex;
            t00 += v0[e] * v0[ep];
            t11 += v1[e] * v1[ep];
            float p = v0[e] * v1[ep];
            t01 += p;
            unsigned sg = ((unsigned)__popc((unsigned)ep & zme) & 1u) << 31;
            u01 += fflip(p, sg ^ bs31);
        }
        float r = fold4(t00, t11, t01, u01, lane);
        if (lane < 4) red[w * 16 + (i - 5) * 4 + lane] = r;
    }
    __syncthreads();
    int t = threadIdx.x;
    if (t < 16) {
        float r = red[t] + red[16 + t] + red[32 + t] + red[48 + t];
        P[PM_OFF + (unsigned)t * 512u + blockIdx.x] = r;
    }
}

// ---- RY layer 2 bits 0..11 + q10..q20 X/Y + ALL Z measurements ----
// 512 threads, 8 elems/thread, 4 exchange phases
__global__ __launch_bounds__(512, 4) void k_low(float* __restrict__ phi,
                                                const float* __restrict__ theta,
                                                float* __restrict__ P) {
    constexpr MaskSet M = buildMasks();
    __shared__ float As[4096];
    __shared__ float Bs[4096];
    __shared__ float redZ[8 * 33];
    __shared__ float redQ[8 * 44];
    __shared__ float trig[4 * NQ];
    float4* As4 = (float4*)As;
    float4* Bs4 = (float4*)Bs;
    int t = threadIdx.x;
    int lane = t & 63, w = t >> 6;
    unsigned base = blockIdx.x * 4096u;
    float a[8], b[8];
    buildTrig(trig, theta, t);

    // ---- P0: load (8 consecutive elems/thread), gates bits 0..2, store ----
    {
        const float4* g0 = (const float4*)(phi + base);
        const float4* g1 = (const float4*)(phi + DIMN + base);
        float4 va0 = g0[2 * t], va1 = g0[2 * t + 1];
        float4 vb0 = g1[2 * t], vb1 = g1[2 * t + 1];
        a[0] = va0.x; a[1] = va0.y; a[2] = va0.z; a[3] = va0.w;
        a[4] = va1.x; a[5] = va1.y; a[6] = va1.z; a[7] = va1.w;
        b[0] = vb0.x; b[1] = vb0.y; b[2] = vb0.z; b[3] = vb0.w;
        b[4] = vb1.x; b[5] = vb1.y; b[6] = vb1.z; b[7] = vb1.w;
        __syncthreads();               // trig ready
        gates3(a, b, trig, 0);
#pragma unroll
        for (int j = 0; j < 8; ++j) {
            unsigned i = ((unsigned)t << 3) | (unsigned)j;
            unsigned A = sA(i);
            As[A] = a[j]; Bs[A] = b[j];
        }
    }
    __syncthreads();

    // ---- X01 read (j = bits 3..5), gates 3..5, write back same addresses ----
    {
#pragma unroll
        for (int j = 0; j < 8; ++j) {
            unsigned i = (((unsigned)t >> 3) << 6) | ((unsigned)j << 3) | ((unsigned)t & 7u);
            unsigned A = sA(i);
            a[j] = As[A]; b[j] = Bs[A];
        }
        gates3(a, b, trig, 3);
#pragma unroll
        for (int j = 0; j < 8; ++j) {
            unsigned i = (((unsigned)t >> 3) << 6) | ((unsigned)j << 3) | ((unsigned)t & 7u);
            unsigned A = sA(i);
            As[A] = a[j]; Bs[A] = b[j];
        }
    }
    __syncthreads();

    // ---- X12 read (j = bits 6..8), gates 6..8, write back ----
    {
#pragma unroll
        for (int j = 0; j < 8; ++j) {
            unsigned i = (((unsigned)t >> 6) << 9) | ((unsigned)j << 6) | ((unsigned)t & 63u);
            unsigned A = sA(i);
            a[j] = As[A]; b[j] = Bs[A];
        }
        gates3(a, b, trig, 6);
#pragma unroll
        for (int j = 0; j < 8; ++j) {
            unsigned i = (((unsigned)t >> 6) << 9) | ((unsigned)j << 6) | ((unsigned)t & 63u);
            unsigned A = sA(i);
            As[A] = a[j]; Bs[A] = b[j];
        }
    }
    __syncthreads();

    // ---- X23 read (j = bits 9..11), gates 9..11 ----
    {
#pragma unroll
        for (int j = 0; j < 8; ++j) {
            unsigned i = ((unsigned)j << 9) | (unsigned)t;
            unsigned A = sA(i);
            a[j] = As[A]; b[j] = Bs[A];
        }
        gates3(a, b, trig, 9);
    }
    __syncthreads();   // protect As/Bs before measurement-layout overwrite

    // ---- write phi + measurement-layout LDS (elem i at i ^ (((i>>8)&3)<<2)) ----
#pragma unroll
    for (int j = 0; j < 8; ++j) {
        unsigned i = ((unsigned)j << 9) | (unsigned)t;
        phi[base + i] = a[j];
        phi[DIMN + base + i] = b[j];
        unsigned p = i ^ (((i >> 8) & 3u) << 2);
        As[p] = a[j]; Bs[p] = b[j];
    }

    // ---- fused Z measurement from regs: 3-level tree (bits 9..11) + lane Walsh ----
#pragma unroll
    for (int c = 0; c < 3; ++c) {
        float p[8];
#pragma unroll
        for (int j = 0; j < 8; ++j)
            p[j] = (c == 0) ? a[j] * a[j] : (c == 1) ? b[j] * b[j] : a[j] * b[j];
        float s1[4], d1[4];
#pragma unroll
        for (int j = 0; j < 4; ++j) { s1[j] = p[j] + p[j + 4]; d1[j] = p[j] - p[j + 4]; }
        float s2_0 = s1[0] + s1[2], s2_1 = s1[1] + s1[3];
        float d2_0 = d1[0] - d1[2], d2_1 = d1[1] - d1[3];
        float SS = s2_0 + s2_1;
        float z0 = (d1[0] + d1[1]) + (d1[2] + d1[3]);     // sign: bit 11
        float z1 = d2_0 + d2_1;                           // sign: bits 11,10
        float d3 = d2_0 - d2_1;                           // sign: bits 11,10,9
        float r = fold4(SS, z0, z1, 0.f, lane);
        if (lane < 3) redZ[w * 33 + c * 11 + lane] = r;
        float v = d3;
#pragma unroll
        for (int s = 0; s < 6; ++s) {
            float u = __shfl_xor(v, 1 << s);
            v = u + fflip(v, ((unsigned)(lane >> s) & 1u) << 31);
        }
        int pcnt = __popc(lane);
        if (lane == 64 - (64 >> pcnt)) redZ[w * 33 + c * 11 + 3 + pcnt] = v;
    }
    __syncthreads();   // redZ + measurement-layout As/Bs visible

    // ---- Z combine over 8 waves with wave-bit signs (elem bits 6..8) ----
    if (t < 66) {
        int c = t % 3, q = t / 3;
        int idx, wm;
        if (q == 0 || q == 21)      { idx = 9; wm = 7; }   // full suffix
        else if (q <= 9)            { idx = 0; wm = 0; }   // SS (suffix above tile)
        else if (q == 10)           { idx = 1; wm = 0; }
        else if (q == 11)           { idx = 2; wm = 0; }
        else if (q == 12)           { idx = 3; wm = 0; }
        else if (q == 13)           { idx = 3; wm = 4; }
        else if (q == 14)           { idx = 3; wm = 6; }
        else if (q == 15)           { idx = 3; wm = 7; }
        else                        { idx = q - 12; wm = 7; }  // q16..q20 -> 4..8
        float val = 0.f;
#pragma unroll
        for (int ww = 0; ww < 8; ++ww) {
            float rv = redZ[ww * 33 + c * 11 + idx];
            val += ((__popc(ww & wm) & 1) ? -rv : rv);
        }
        unsigned sg = (unsigned)__popc(base & M.zm[q]) & 1u;
        P[PL_OFF + (44u + (unsigned)t) * 1024u + blockIdx.x] = sg ? -val : val;
    }

    // ---- q10,q11 from registers (x-pairs within bits 9..11 = j bits) ----
#pragma unroll
    for (int i = 0; i < 2; ++i) {
        int q = 10 + i;
        unsigned je  = (M.xm[q] >> 9) & 7u;
        unsigned zmj = (M.zm[q] >> 9) & 7u;
        unsigned zb31 = ((unsigned)__popc(base & M.zm[q]) & 1u) << 31;
        float t00 = 0.f, t11 = 0.f, t01 = 0.f, u01 = 0.f;
#pragma unroll
        for (int j = 0; j < 8; ++j) {
            int jp = j ^ (int)je;
            t00 += a[j] * a[jp];
            t11 += b[j] * b[jp];
            float p = a[j] * b[jp];
            t01 += p;
            unsigned sg = ((unsigned)__popc((unsigned)jp & zmj) & 1u) << 31;
            u01 += fflip(p, sg ^ zb31);
        }
        float r = fold4(t00, t11, t01, u01, lane);
        if (lane < 4) redQ[w * 44 + 4 * i + lane] = r;
    }

    // ---- q12..q19 (generic float4-pair path), q20 special ----
#pragma unroll
    for (int iq = 2; iq < 10; ++iq) {
        int q = 10 + iq;
        unsigned m = M.xm[q], zm = M.zm[q];
        unsigned zb = (unsigned)__popc(base & zm) & 1u;
        int gb = topbit_c(M.xm[q]) - 2;
        unsigned mg4 = m >> 2;
        unsigned swap2 = m & 3u;            // 0 or 2
        float t00 = 0.f, t11 = 0.f, t01 = 0.f, u01 = 0.f;
        unsigned gc = (unsigned)t;          // 0..511: covers all 512 half-pairs
        unsigned g = ((gc >> gb) << (gb + 1)) | (gc & ((1u << gb) - 1u));
        unsigned gx = g ^ mg4;
        float4 a0 = As4[ph4(g)],  a1 = Bs4[ph4(g)];
        float4 b0 = As4[ph4(gx)], b1 = Bs4[ph4(gx)];
        if (swap2) {
            b0 = make_float4(b0.z, b0.w, b0.x, b0.y);
            b1 = make_float4(b1.z, b1.w, b1.x, b1.y);
        }
        unsigned szg = ((unsigned)__popc((g << 2) & zm) + zb) & 1u;
        unsigned szx = ((unsigned)__popc((gx << 2) & zm) + zb) & 1u;
        unsigned fg = szg << 31, fx = szx << 31;
        const float* A0 = &a0.x; const float* A1 = &a1.x;
        const float* B0 = &b0.x; const float* B1 = &b1.x;
#pragma unroll
        for (int j = 0; j < 4; ++j) {
            t00 += A0[j] * B0[j];
            t11 += A1[j] * B1[j];
            float p = A0[j] * B1[j], r2 = B0[j] * A1[j];
            t01 += p + r2;
            u01 += fflip(p, fx) + fflip(r2, fg);
        }
        t00 *= 2.f; t11 *= 2.f;
        float r = fold4(t00, t11, t01, u01, lane);
        if (lane < 4) redQ[w * 44 + 4 * iq + lane] = r;
    }
    {
        // q20: m = 3, partner within float4; zm&3 == 2
        unsigned zm = M.zm[20];
        unsigned zb = (unsigned)__popc(base & zm) & 1u;
        float t00 = 0.f, t11 = 0.f, t01 = 0.f, u01 = 0.f;
#pragma unroll
        for (int k = 0; k < 2; ++k) {
            unsigned g = (unsigned)t + 512u * k;
            float4 a0 = As4[ph4(g)], a1 = Bs4[ph4(g)];
            unsigned szg = ((unsigned)__popc((g << 2) & zm) + zb) & 1u;
            const float* A0 = &a0.x; const float* A1 = &a1.x;
#pragma unroll
            for (int j = 0; j < 4; ++j) {
                int jx = j ^ 3;
                float p = A0[j] * A0[jx];
                float q2 = A1[j] * A1[jx];
                float cr = A0[j] * A1[jx];
                t00 += p; t11 += q2; t01 += cr;
                unsigned sj = ((unsigned)(jx >> 1) & 1u) ^ szg;   // zm&3 == 2
                u01 += fflip(cr, sj << 31);
            }
        }
        float r = fold4(t00, t11, t01, u01, lane);
        if (lane < 4) redQ[w * 44 + 40 + lane] = r;
    }
    __syncthreads();
    if (t < 44) {
        float r = 0.f;
#pragma unroll
        for (int ww = 0; ww < 8; ++ww) r += redQ[ww * 44 + t];
        P[PL_OFF + (unsigned)t * 1024u + blockIdx.x] = r;
    }
}

// ------- X/Y slice measurements (baseline k_measS structure) + FINAL reduce ------
// grid (256, 3): slice 0 = q0+q21 (shared loads), slice 1 = q4, slice 2 = q9.
// Per thread: 8 independent iterations of 4 coalesced float4 loads (proven MLP).
__global__ __launch_bounds__(256) void k_measF(const float* __restrict__ phi,
                                               float* __restrict__ P,
                                               float* __restrict__ out) {
    constexpr MaskSet M = buildMasks();
    __shared__ float red[4 * 8];
    __shared__ float accv[160];
    __shared__ int lastBlk;
    const float4* P0 = (const float4*)phi;
    const float4* P1 = (const float4*)(phi + DIMN);
    int t = threadIdx.x, lane = t & 63, w = t >> 6;
    int slice = blockIdx.y;
    unsigned m, zmA, zmB = 0; int gb;
    if (slice == 0)      { m = M.xm[0]; gb = 19; zmA = M.zm[0]; zmB = M.zm[21]; }
    else if (slice == 1) { m = M.xm[4]; gb = 15; zmA = M.zm[4]; }
    else                 { m = M.xm[9]; gb = 10; zmA = M.zm[9]; }
    unsigned mg4 = m >> 2;
    unsigned tid = blockIdx.x * 256u + (unsigned)t;        // [0, 65536)
    float acc0[4] = { 0.f, 0.f, 0.f, 0.f };
    float acc1[4] = { 0.f, 0.f, 0.f, 0.f };
#pragma unroll
    for (int it = 0; it < 8; ++it) {
        unsigned gc = tid + (unsigned)it * 65536u;         // [0, 2^19)
        unsigned g = ((gc >> gb) << (gb + 1)) | (gc & ((1u << gb) - 1u));
        unsigned gx = g ^ mg4;
        float4 a0 = P0[g], a1 = P1[g];
        float4 b0 = P0[gx], b1 = P1[gx];
        accPair(a0, a1, b0, b1, g, gx, 0u, zmA, acc0);
        if (slice == 0) accPair(a0, a1, b0, b1, g, gx, 1u, zmB, acc1);
    }
    acc0[0] *= 2.f; acc0[1] *= 2.f;
    acc1[0] *= 2.f; acc1[1] *= 2.f;
    {
        float r = fold4(acc0[0], acc0[1], acc0[2], acc0[3], lane);
        if (lane < 4) red[w * 8 + lane] = r;
        if (slice == 0) {
            float r1 = fold4(acc1[0], acc1[1], acc1[2], acc1[3], lane);
            if (lane < 4) red[w * 8 + 4 + lane] = r1;
        }
    }
    __syncthreads();
    int nrow = (slice == 0) ? 8 : 4;
    if (t < nrow) {
        float r = red[t] + red[8 + t] + red[16 + t] + red[24 + t];
        int row = (slice == 0) ? t : (slice == 1 ? 8 + t : 12 + t);
        P[PF_OFF + (unsigned)row * 512u + blockIdx.x] = r;          // value
        P[PF_OFF + (unsigned)row * 512u + 256u + blockIdx.x] = 0.f; // zero pad
    }
    // ---- ticket: last of 768 blocks does the final reduction + loss ----
    __threadfence();
    __syncthreads();
    if (t == 0) {
        int c = atomicAdd((int*)(P + CNT_OFF), 1);
        lastBlk = (c == 768 - 1);
    }
    __syncthreads();
    if (!lastBlk) return;
    __threadfence();

    // ---- wave-parallel coalesced reduce of 264 flat segments (512 floats each) ----
    if (t < 160) accv[t] = 0.f;
    __syncthreads();
    {
        const float4* Pf = (const float4*)P;
        int g0w = (w < 2) ? w * 17 : 34 + (w - 2) * 16;    // groups of 4 segments
        int ng  = (w < 2) ? 17 : 16;                       // 17+17+16+16 = 66 = 264/4
        for (int gi = 0; gi < ng; ++gi) {
            int s0 = (g0w + gi) * 4;
            float q[4];
#pragma unroll
            for (int k = 0; k < 4; ++k) {
                const float4* sp = Pf + (unsigned)(s0 + k) * 128u;
                float4 x = sp[lane];
                float4 y = sp[lane + 64];
                q[k] = ((x.x + x.y) + (x.z + x.w)) + ((y.x + y.y) + (y.z + y.w));
            }
            float r = fold4(q[0], q[1], q[2], q[3], lane);
            if (lane < 4) atomicAdd(&accv[slotOf(s0 + lane)], r);
        }
    }
    __syncthreads();
    float v = 0.f;
    if (t < NQ) {
        float t00 = accv[4 * t], t11 = accv[4 * t + 1];
        float t01 = accv[4 * t + 2], u01 = accv[4 * t + 3];
        float d = t00 - t11;
        v = 0.5f * d * d + 2.f * t01 * t01 + 2.f * u01 * u01;   // X op + Y op
    } else if (t < 2 * NQ) {
        int q = t - NQ;
        float z0 = accv[88 + 3 * q], z1 = accv[88 + 3 * q + 1];
        float zz = accv[88 + 3 * q + 2];
        float d = z0 - z1;
        v = 0.5f * d * d + 2.f * zz * zz;                       // Z op
    }
    v += __shfl_down(v, 32); v += __shfl_down(v, 16); v += __shfl_down(v, 8);
    v += __shfl_down(v, 4);  v += __shfl_down(v, 2);  v += __shfl_down(v, 1);
    if (t == 0) out[0] = v;
}

extern "C" void kernel_launch(void* const* d_in, const int* in_sizes, int n_in,
                              void* d_out, int out_size, void* d_ws, size_t ws_size,
                              hipStream_t stream) {
    const float* theta = (const float*)d_in[0];
    float* out  = (float*)d_out;
    float* ws   = (float*)d_ws;
    float* phi  = ws;                          // 2 * DIMN floats (32 MB)
    float* P    = ws + 2 * (size_t)DIMN;       // partials + ticket counter

    k_genHi<<<512, 256, 0, stream>>>(phi, theta, P);
    k_midA<<<512, 256, 0, stream>>>(phi, theta, P);
    k_low<<<1024, 512, 0, stream>>>(phi, theta, P);
    k_measF<<<dim3(256, 3), 256, 0, stream>>>(phi, P, out);
}